// Round 9
// baseline (453.331 us; speedup 1.0000x reference)
//
#include <hip/hip_runtime.h>
#include <hip/hip_bf16.h>

#define NGRAPH 64
#define NGENES 16000
#define NANNOT 8000
#define NNODES 10000
#define NTOT   (NGRAPH * NNODES)
#define DEG    4
#define NEDGE  (NGRAPH * NNODES * DEG)
#define KSEL   5000
#define FIXS   1048576.0f

#define KSPLIT 2
#define KSTEP  64
#define KSTEPS (NGENES / KSPLIT / KSTEP)   // 125
#define LDSROW 68                          // 64 + 4 pad ushorts

typedef __attribute__((ext_vector_type(8))) short bf16x8;
typedef __attribute__((ext_vector_type(4))) float f32x4;

__device__ __forceinline__ unsigned short f2bf(float x) {
  __hip_bfloat16 h = __float2bfloat16(x);
  return __builtin_bit_cast(unsigned short, h);
}
__device__ __forceinline__ float bf2f(unsigned short u) {
  unsigned int v = (unsigned int)u << 16;
  return __builtin_bit_cast(float, v);
}

// ---------------- kernel B: masked fc1, bf16x3 MFMA, 512B paired bursts -------------
// partials[ksp][64 b][8000 a] = tr[64 x kslice] * (w .* adj)^T[kslice x 8000]
__global__ __launch_bounds__(256, 1) void fc1_kernel(
    const float* __restrict__ tr, const float* __restrict__ w,
    const float* __restrict__ mk, float* __restrict__ partials) {
  __shared__ unsigned short sAh[2][64 * LDSROW];
  __shared__ unsigned short sAl[2][64 * LDSROW];
  __shared__ unsigned short sBh[2][64 * LDSROW];
  __shared__ unsigned short sBl[2][64 * LDSROW];

  const int t = threadIdx.x;
  const int abase = blockIdx.x * 64;                 // 125 * 64 = 8000
  const int kbeg  = blockIdx.y * (NGENES / KSPLIT);  // 0 or 8000
  const int wv = t >> 6, lane = t & 63, lr = lane & 15, ls = lane >> 4;

  // staging: 16 lanes per row (256B/instr), rows r0+16p; pair = +64 floats
  const int r0 = t >> 4, c0 = t & 15;
  size_t gT[4], gB[4];
  int offL[4];
#pragma unroll
  for (int p = 0; p < 4; ++p) {
    int row = r0 + 16 * p;
    gT[p] = (size_t)row * NGENES + c0 * 4;
    gB[p] = (size_t)(abase + row) * NGENES + c0 * 4;
    offL[p] = row * LDSROW + c0 * 4;
  }

  float4 rt0[4], rw0[4], ra0[4];   // step s   (k0)
  float4 rt1[4], rw1[4], ra1[4];   // step s+1 (k0+64)

  auto load_pair = [&](int k0) {
#pragma unroll
    for (int p = 0; p < 4; ++p) {
      rt0[p] = *(const float4*)&tr[gT[p] + k0];
      rt1[p] = *(const float4*)&tr[gT[p] + k0 + KSTEP];
      rw0[p] = *(const float4*)&w [gB[p] + k0];
      rw1[p] = *(const float4*)&w [gB[p] + k0 + KSTEP];
      ra0[p] = *(const float4*)&mk[gB[p] + k0];
      ra1[p] = *(const float4*)&mk[gB[p] + k0 + KSTEP];
    }
  };
  auto load_single = [&](int k0) {
#pragma unroll
    for (int p = 0; p < 4; ++p) {
      rt0[p] = *(const float4*)&tr[gT[p] + k0];
      rw0[p] = *(const float4*)&w [gB[p] + k0];
      ra0[p] = *(const float4*)&mk[gB[p] + k0];
    }
  };
  auto cvt4 = [&](unsigned short* hp, unsigned short* lp, int off, float4 v) {
    ushort4 h, l;
    h.x = f2bf(v.x); l.x = f2bf(v.x - bf2f(h.x));
    h.y = f2bf(v.y); l.y = f2bf(v.y - bf2f(h.y));
    h.z = f2bf(v.z); l.z = f2bf(v.z - bf2f(h.z));
    h.w = f2bf(v.w); l.w = f2bf(v.w - bf2f(h.w));
    *(ushort4*)&hp[off] = h;
    *(ushort4*)&lp[off] = l;
  };
  auto store_set0 = [&](int buf) {
#pragma unroll
    for (int p = 0; p < 4; ++p) {
      cvt4(sAh[buf], sAl[buf], offL[p], rt0[p]);
      float4 pr = make_float4(rw0[p].x * ra0[p].x, rw0[p].y * ra0[p].y,
                              rw0[p].z * ra0[p].z, rw0[p].w * ra0[p].w);
      cvt4(sBh[buf], sBl[buf], offL[p], pr);
    }
  };
  auto store_set1 = [&](int buf) {
#pragma unroll
    for (int p = 0; p < 4; ++p) {
      cvt4(sAh[buf], sAl[buf], offL[p], rt1[p]);
      float4 pr = make_float4(rw1[p].x * ra1[p].x, rw1[p].y * ra1[p].y,
                              rw1[p].z * ra1[p].z, rw1[p].w * ra1[p].w);
      cvt4(sBh[buf], sBl[buf], offL[p], pr);
    }
  };

  f32x4 acc[4];
#pragma unroll
  for (int mt = 0; mt < 4; ++mt)
#pragma unroll
    for (int r = 0; r < 4; ++r) acc[mt][r] = 0.f;

  const int fbA = lr * LDSROW + ls * 8;
  const int fbB = (wv * 16 + lr) * LDSROW + ls * 8;

  auto compute = [&](int buf) {
#pragma unroll
    for (int ks = 0; ks < 2; ++ks) {
      bf16x8 bh = *(const bf16x8*)&sBh[buf][fbB + ks * 32];
      bf16x8 bl = *(const bf16x8*)&sBl[buf][fbB + ks * 32];
#pragma unroll
      for (int mt = 0; mt < 4; ++mt) {
        bf16x8 ah = *(const bf16x8*)&sAh[buf][mt * 16 * LDSROW + fbA + ks * 32];
        bf16x8 al = *(const bf16x8*)&sAl[buf][mt * 16 * LDSROW + fbA + ks * 32];
        acc[mt] = __builtin_amdgcn_mfma_f32_16x16x32_bf16(ah, bh, acc[mt], 0, 0, 0);
        acc[mt] = __builtin_amdgcn_mfma_f32_16x16x32_bf16(ah, bl, acc[mt], 0, 0, 0);
        acc[mt] = __builtin_amdgcn_mfma_f32_16x16x32_bf16(al, bh, acc[mt], 0, 0, 0);
      }
    }
  };

  // prologue: steps 0,1 staged; steps 2,3 in regs
  load_pair(kbeg);
  store_set0(0);
  store_set1(1);
  load_pair(kbeg + 2 * KSTEP);
  __syncthreads();

  // 62 pair-iterations cover steps 0..123; step 124 handled in the tail
#pragma unroll 1
  for (int p = 0; p < 62; ++p) {
    compute(0);                        // step 2p
    compute(1);                        // step 2p+1
    __syncthreads();
    store_set0(0);                     // step 2p+2 -> buf0
    if (p < 61) store_set1(1);         // step 2p+3 -> buf1
    if (p < 60)      load_pair(kbeg + (2 * p + 4) * KSTEP);
    else if (p == 60) load_single(kbeg + 124 * KSTEP);
    __syncthreads();
  }
  compute(0);                          // step 124

  // epilogue: D col = lane&15, row = (lane>>4)*4 + reg   [m89-verified]
  float* P = partials + (size_t)blockIdx.y * (64 * NANNOT);
  const int acol = abase + wv * 16 + lr;
#pragma unroll
  for (int mt = 0; mt < 4; ++mt) {
#pragma unroll
    for (int r = 0; r < 4; ++r) {
      int b = mt * 16 + ls * 4 + r;
      P[(size_t)b * NANNOT + acol] = acc[mt][r];
    }
  }
}

// ---------------- kernel B2: finalize xg + zero aggregation buffers ----------------
__global__ void finalize_kernel(const float* __restrict__ partials,
                                const float* __restrict__ fc1_b,
                                const float* __restrict__ x,
                                float* __restrict__ xg,
                                int* __restrict__ g_sum,
                                int* __restrict__ g_deg) {
  int idx = blockIdx.x * blockDim.x + threadIdx.x;
  if (idx >= NTOT) return;
  int b = idx / NNODES, local = idx % NNODES;
  float s;
  if (local < NANNOT) {
    s = fc1_b[local];
    int pidx = b * NANNOT + local;
#pragma unroll
    for (int sp = 0; sp < KSPLIT; ++sp) s += partials[(size_t)sp * (64 * NANNOT) + pidx];
  } else {
    s = x[idx];
  }
  xg[idx] = s;
  g_sum[idx] = 0;
  g_deg[idx] = 0;
}

// ---------------- kernel C1: grid-wide edge aggregation (int atomics, det) ---------
__global__ void agg_kernel(const int* __restrict__ ei, const float* __restrict__ xg,
                           int* __restrict__ g_sum, int* __restrict__ g_deg) {
  int q = blockIdx.x * blockDim.x + threadIdx.x;
  if (q >= NEDGE / 4) return;
  int4 s4 = ((const int4*)ei)[q];
  int4 d4 = ((const int4*)(ei + NEDGE))[q];
#pragma unroll
  for (int u = 0; u < 4; ++u) {
    int s = (&s4.x)[u];
    int d = (&d4.x)[u];
    float v = ((unsigned)s < (unsigned)NTOT) ? xg[s] : 0.f;
    if ((unsigned)d < (unsigned)NTOT) {
      atomicAdd(&g_sum[d], __float2int_rn(v * FIXS));
      atomicAdd(&g_deg[d], 1);
    }
  }
}

// ---------------- kernel C2: per-graph h + radix-select + fc2 ----------------------
__global__ __launch_bounds__(1024) void select_kernel(
    const int* __restrict__ g_sum, const int* __restrict__ g_deg,
    const float* __restrict__ xg,
    const float* __restrict__ wrp, const float* __restrict__ wnp,
    const float* __restrict__ pbp, const float* __restrict__ fc2w,
    const float* __restrict__ fc2b, float* __restrict__ out) {
  const int g = blockIdx.x;
  const int t = threadIdx.x;
  __shared__ float s_h[NNODES];
  __shared__ int s_hist[256];
  __shared__ int s_cnt[1024];
  __shared__ float s_red[1024];
  __shared__ unsigned s_pfx;
  __shared__ int s_rem;

  const int base = g * NNODES;
  const float wr = wrp[0], wn = wnp[0], pb = pbp[0];
  for (int i = t; i < NNODES; i += 1024) {
    int dg = g_deg[base + i];
    float mean = ((float)g_sum[base + i] * (1.0f / FIXS)) / (float)(dg > 0 ? dg : 1);
    s_h[i] = wr * xg[base + i] + wn * mean + pb;
  }
  __syncthreads();

  // radix-select the KSEL-th largest |h|; digit via parallel suffix-scan
  unsigned prefix = 0; int rem = KSEL;
  for (int byte = 3; byte >= 0; --byte) {
    const int sh = byte * 8;
    const unsigned himask = (byte == 3) ? 0u : (0xFFFFFFFFu << (sh + 8));
    if (t < 256) s_hist[t] = 0;
    __syncthreads();
    for (int i = t; i < NNODES; i += 1024) {
      unsigned kk = __float_as_uint(fabsf(s_h[i]));
      if ((kk & himask) == prefix) atomicAdd(&s_hist[(kk >> sh) & 255], 1);
    }
    __syncthreads();
    if (t < 256) s_cnt[t] = s_hist[t];
    __syncthreads();
    for (int off = 1; off < 256; off <<= 1) {
      int v = 0;
      if (t < 256 && t + off < 256) v = s_cnt[t + off];
      __syncthreads();
      if (t < 256) s_cnt[t] += v;
      __syncthreads();
    }
    if (t < 256) {
      int ge = s_cnt[t];
      int ge_next = (t == 255) ? 0 : s_cnt[t + 1];
      if (ge >= rem && ge_next < rem) {
        s_pfx = prefix | ((unsigned)t << sh);
        s_rem = rem - ge_next;
      }
    }
    __syncthreads();
    prefix = s_pfx; rem = s_rem;
    __syncthreads();
  }
  const unsigned T = prefix;
  const int needed = rem;

  // prefix-rank over ==T elements (lowest-index tie-break, matches jax top_k)
  const int CH = 10;
  int i0 = t * CH;
  int i1 = i0 + CH; if (i1 > NNODES) i1 = NNODES;
  int loc = 0;
  for (int i = i0; i < i1; ++i)
    loc += (__float_as_uint(fabsf(s_h[i])) == T) ? 1 : 0;
  s_cnt[t] = loc;
  __syncthreads();
  for (int off = 1; off < 1024; off <<= 1) {
    int v = (t >= off) ? s_cnt[t - off] : 0;
    __syncthreads();
    s_cnt[t] += v;
    __syncthreads();
  }
  int rank = s_cnt[t] - loc;

  float a0 = 0.f, a1 = 0.f;
  for (int i = i0; i < i1; ++i) {
    float h = s_h[i];
    unsigned kk = __float_as_uint(fabsf(h));
    bool inc = false;
    if (kk > T) inc = true;
    else if (kk == T) { inc = (rank < needed); ++rank; }
    if (inc) {
      a0 += h * fc2w[i];
      a1 += h * fc2w[NNODES + i];
    }
  }
  s_red[t] = a0; __syncthreads();
  for (int off = 512; off > 0; off >>= 1) {
    if (t < off) s_red[t] += s_red[t + off];
    __syncthreads();
  }
  float r0 = s_red[0];
  __syncthreads();
  s_red[t] = a1; __syncthreads();
  for (int off = 512; off > 0; off >>= 1) {
    if (t < off) s_red[t] += s_red[t + off];
    __syncthreads();
  }
  if (t == 0) {
    out[g * 2 + 0] = r0 + fc2b[0];
    out[g * 2 + 1] = s_red[0] + fc2b[1];
  }
}

// ---------------- launch ----------------
extern "C" void kernel_launch(void* const* d_in, const int* in_sizes, int n_in,
                              void* d_out, int out_size, void* d_ws, size_t ws_size,
                              hipStream_t stream) {
  const float* tr  = (const float*)d_in[0];
  const float* x   = (const float*)d_in[1];
  const int*   ei  = (const int*)d_in[2];
  const float* adj = (const float*)d_in[4];
  const float* w1  = (const float*)d_in[5];
  const float* b1  = (const float*)d_in[6];
  const float* wr  = (const float*)d_in[7];
  const float* wn  = (const float*)d_in[8];
  const float* pb  = (const float*)d_in[9];
  const float* w2  = (const float*)d_in[10];
  const float* b2  = (const float*)d_in[11];

  char* ws = (char*)d_ws;
  float* xg       = (float*)ws;                                  // 2.56 MB
  float* partials = (float*)(ws + (size_t)NTOT * 4);             // 4.1 MB
  int*   g_sum    = (int*)(ws + (size_t)NTOT * 4 + (size_t)KSPLIT * 64 * NANNOT * 4);
  int*   g_deg    = g_sum + NTOT;
  float* out = (float*)d_out;

  dim3 g1(NANNOT / 64, KSPLIT);   // 125 x 2 = 250 blocks
  fc1_kernel<<<g1, 256, 0, stream>>>(tr, w1, adj, partials);
  finalize_kernel<<<(NTOT + 255) / 256, 256, 0, stream>>>(partials, b1, x, xg, g_sum, g_deg);
  agg_kernel<<<(NEDGE / 4 + 255) / 256, 256, 0, stream>>>(ei, xg, g_sum, g_deg);
  select_kernel<<<NGRAPH, 1024, 0, stream>>>(g_sum, g_deg, xg, wr, wn, pb, w2, b2, out);
}

// Round 10
// 273.973 us; speedup vs baseline: 1.6547x; 1.6547x over previous
//
#include <hip/hip_runtime.h>
#include <hip/hip_bf16.h>

#define NGRAPH 64
#define NGENES 16000
#define NANNOT 8000
#define NNODES 10000
#define NTOT   (NGRAPH * NNODES)
#define DEG    4
#define NEDGE  (NGRAPH * NNODES * DEG)
#define KSEL   5000
#define FIXS   1048576.0f

#define KSPLIT 2
#define KSTEP  64
#define KSTEPS (NGENES / KSPLIT / KSTEP)   // 125
#define LDSROW 68                          // 64 + 4 pad ushorts

typedef __attribute__((ext_vector_type(8))) short bf16x8;
typedef __attribute__((ext_vector_type(4))) float f32x4;

__device__ __forceinline__ unsigned short f2bf(float x) {
  __hip_bfloat16 h = __float2bfloat16(x);
  return __builtin_bit_cast(unsigned short, h);
}
__device__ __forceinline__ float bf2f(unsigned short u) {
  unsigned int v = (unsigned int)u << 16;
  return __builtin_bit_cast(float, v);
}

// ---------------- kernel B: masked fc1 via bf16x3 MFMA (round-8 proven) -------------
// partials[ksp][64 b][8000 a] = tr[64 x kslice] * (w .* adj)^T[kslice x 8000]
__global__ __launch_bounds__(256, 1) void fc1_kernel(
    const float* __restrict__ tr, const float* __restrict__ w,
    const float* __restrict__ mk, float* __restrict__ partials) {
  __shared__ unsigned short sAh[2][64 * LDSROW];
  __shared__ unsigned short sAl[2][64 * LDSROW];
  __shared__ unsigned short sBh[2][64 * LDSROW];
  __shared__ unsigned short sBl[2][64 * LDSROW];

  const int t = threadIdx.x;
  const int abase = blockIdx.x * 64;                 // 125 * 64 = 8000
  const int kbeg  = blockIdx.y * (NGENES / KSPLIT);  // 0 or 8000
  const int wv = t >> 6, lane = t & 63, lr = lane & 15, ls = lane >> 4;

  const int r0 = t >> 4, c0 = t & 15;
  size_t gT[4], gB[4];
  int offL[4];
#pragma unroll
  for (int p = 0; p < 4; ++p) {
    int row = r0 + 16 * p;
    gT[p] = (size_t)row * NGENES + c0 * 4;
    gB[p] = (size_t)(abase + row) * NGENES + c0 * 4;
    offL[p] = row * LDSROW + c0 * 4;
  }

  float4 rt[4], rw[4], ra[4];

  auto load_step = [&](int k0) {
#pragma unroll
    for (int p = 0; p < 4; ++p) {
      rt[p] = *(const float4*)&tr[gT[p] + k0];
      rw[p] = *(const float4*)&w [gB[p] + k0];
      ra[p] = *(const float4*)&mk[gB[p] + k0];
    }
  };
  auto cvt4 = [&](unsigned short* hp, unsigned short* lp, int off, float4 v) {
    ushort4 h, l;
    h.x = f2bf(v.x); l.x = f2bf(v.x - bf2f(h.x));
    h.y = f2bf(v.y); l.y = f2bf(v.y - bf2f(h.y));
    h.z = f2bf(v.z); l.z = f2bf(v.z - bf2f(h.z));
    h.w = f2bf(v.w); l.w = f2bf(v.w - bf2f(h.w));
    *(ushort4*)&hp[off] = h;
    *(ushort4*)&lp[off] = l;
  };
  auto store_step = [&](int buf) {
#pragma unroll
    for (int p = 0; p < 4; ++p) {
      cvt4(sAh[buf], sAl[buf], offL[p], rt[p]);
      float4 pr = make_float4(rw[p].x * ra[p].x, rw[p].y * ra[p].y,
                              rw[p].z * ra[p].z, rw[p].w * ra[p].w);
      cvt4(sBh[buf], sBl[buf], offL[p], pr);
    }
  };

  f32x4 acc[4];
#pragma unroll
  for (int mt = 0; mt < 4; ++mt)
#pragma unroll
    for (int r = 0; r < 4; ++r) acc[mt][r] = 0.f;

  load_step(kbeg);
  store_step(0);
  load_step(kbeg + KSTEP);
  __syncthreads();

  const int fbA = lr * LDSROW + ls * 8;
  const int fbB = (wv * 16 + lr) * LDSROW + ls * 8;

#pragma unroll 1
  for (int s = 0; s < KSTEPS; ++s) {
    const int buf = s & 1;
#pragma unroll
    for (int ks = 0; ks < 2; ++ks) {
      bf16x8 bh = *(const bf16x8*)&sBh[buf][fbB + ks * 32];
      bf16x8 bl = *(const bf16x8*)&sBl[buf][fbB + ks * 32];
#pragma unroll
      for (int mt = 0; mt < 4; ++mt) {
        bf16x8 ah = *(const bf16x8*)&sAh[buf][mt * 16 * LDSROW + fbA + ks * 32];
        bf16x8 al = *(const bf16x8*)&sAl[buf][mt * 16 * LDSROW + fbA + ks * 32];
        acc[mt] = __builtin_amdgcn_mfma_f32_16x16x32_bf16(ah, bh, acc[mt], 0, 0, 0);
        acc[mt] = __builtin_amdgcn_mfma_f32_16x16x32_bf16(ah, bl, acc[mt], 0, 0, 0);
        acc[mt] = __builtin_amdgcn_mfma_f32_16x16x32_bf16(al, bh, acc[mt], 0, 0, 0);
      }
    }
    if (s + 1 < KSTEPS) {
      store_step(buf ^ 1);
      if (s + 2 < KSTEPS) load_step(kbeg + (s + 2) * KSTEP);
    }
    __syncthreads();
  }

  // epilogue: D col = lane&15, row = (lane>>4)*4 + reg   [m89-verified]
  float* P = partials + (size_t)blockIdx.y * (64 * NANNOT);
  const int acol = abase + wv * 16 + lr;
#pragma unroll
  for (int mt = 0; mt < 4; ++mt) {
#pragma unroll
    for (int r = 0; r < 4; ++r) {
      int b = mt * 16 + ls * 4 + r;
      P[(size_t)b * NANNOT + acol] = acc[mt][r];
    }
  }
}

// ---------------- kernel B2: finalize xg (init + deterministic k-split reduce) -----
__global__ void finalize_kernel(const float* __restrict__ partials,
                                const float* __restrict__ fc1_b,
                                const float* __restrict__ x,
                                float* __restrict__ xg) {
  int idx = blockIdx.x * blockDim.x + threadIdx.x;
  if (idx >= NTOT) return;
  int b = idx / NNODES, local = idx % NNODES;
  float s;
  if (local < NANNOT) {
    s = fc1_b[local];
    int pidx = b * NANNOT + local;
#pragma unroll
    for (int sp = 0; sp < KSPLIT; ++sp) s += partials[(size_t)sp * (64 * NANNOT) + pidx];
  } else {
    s = x[idx];
  }
  xg[idx] = s;
}

// ---------------- kernel C1: edge aggregation, 4 blocks/graph, LDS atomics ---------
// Each block owns a quarter of one graph's edges; writes private partial arrays
// with plain stores (no global atomics -> no cross-XCD serialization, deterministic).
__global__ __launch_bounds__(1024) void agg_kernel(
    const int* __restrict__ ei, const float* __restrict__ xg,
    int* __restrict__ part_sum, int* __restrict__ part_deg) {
  const int blk = blockIdx.x;          // 0..255
  const int g = blk >> 2, q = blk & 3;
  const int t = threadIdx.x;
  __shared__ int s_sum[NNODES];
  __shared__ int s_deg[NNODES];
  for (int i = t; i < NNODES; i += 1024) { s_sum[i] = 0; s_deg[i] = 0; }
  __syncthreads();

  const int ebase = g * (NNODES * DEG) + q * (NNODES * DEG / 4);  // int4-aligned
  const int base = g * NNODES;
  const int4* src4 = (const int4*)(ei + ebase);
  const int4* dst4 = (const int4*)(ei + NEDGE + ebase);
  const int nq = (NNODES * DEG / 4) / 4;   // 2500 int4 per quarter
  for (int v = t; v < nq; v += 1024) {
    int4 s4 = src4[v];
    int4 d4 = dst4[v];
#pragma unroll
    for (int u = 0; u < 4; ++u) {
      int s = (&s4.x)[u];
      int d = (&d4.x)[u];
      float vv = ((unsigned)s < (unsigned)NTOT) ? xg[s] : 0.f;
      unsigned dl = (unsigned)(d - base);
      if (dl < (unsigned)NNODES) {
        atomicAdd(&s_sum[dl], __float2int_rn(vv * FIXS));
        atomicAdd(&s_deg[dl], 1);
      }
    }
  }
  __syncthreads();

  int* ps = part_sum + (size_t)blk * NNODES;
  int* pd = part_deg + (size_t)blk * NNODES;
  for (int i = t; i < NNODES; i += 1024) { ps[i] = s_sum[i]; pd[i] = s_deg[i]; }
}

// ---------------- kernel C2: per-graph h + radix-select + fc2 ----------------------
__global__ __launch_bounds__(1024) void select_kernel(
    const int* __restrict__ part_sum, const int* __restrict__ part_deg,
    const float* __restrict__ xg,
    const float* __restrict__ wrp, const float* __restrict__ wnp,
    const float* __restrict__ pbp, const float* __restrict__ fc2w,
    const float* __restrict__ fc2b, float* __restrict__ out) {
  const int g = blockIdx.x;
  const int t = threadIdx.x;
  __shared__ float s_h[NNODES];
  __shared__ int s_hist[256];
  __shared__ int s_cnt[1024];
  __shared__ float s_red[1024];
  __shared__ unsigned s_pfx;
  __shared__ int s_rem;

  const int base = g * NNODES;
  const float wr = wrp[0], wn = wnp[0], pb = pbp[0];
  for (int i = t; i < NNODES; i += 1024) {
    int sum = 0, dg = 0;
#pragma unroll
    for (int q = 0; q < 4; ++q) {
      size_t off = (size_t)(g * 4 + q) * NNODES + i;
      sum += part_sum[off];
      dg  += part_deg[off];
    }
    float mean = ((float)sum * (1.0f / FIXS)) / (float)(dg > 0 ? dg : 1);
    s_h[i] = wr * xg[base + i] + wn * mean + pb;
  }
  __syncthreads();

  // radix-select the KSEL-th largest |h|; digit via parallel suffix-scan
  unsigned prefix = 0; int rem = KSEL;
  for (int byte = 3; byte >= 0; --byte) {
    const int sh = byte * 8;
    const unsigned himask = (byte == 3) ? 0u : (0xFFFFFFFFu << (sh + 8));
    if (t < 256) s_hist[t] = 0;
    __syncthreads();
    for (int i = t; i < NNODES; i += 1024) {
      unsigned kk = __float_as_uint(fabsf(s_h[i]));
      if ((kk & himask) == prefix) atomicAdd(&s_hist[(kk >> sh) & 255], 1);
    }
    __syncthreads();
    if (t < 256) s_cnt[t] = s_hist[t];
    __syncthreads();
    for (int off = 1; off < 256; off <<= 1) {
      int v = 0;
      if (t < 256 && t + off < 256) v = s_cnt[t + off];
      __syncthreads();
      if (t < 256) s_cnt[t] += v;
      __syncthreads();
    }
    if (t < 256) {
      int ge = s_cnt[t];
      int ge_next = (t == 255) ? 0 : s_cnt[t + 1];
      if (ge >= rem && ge_next < rem) {
        s_pfx = prefix | ((unsigned)t << sh);
        s_rem = rem - ge_next;
      }
    }
    __syncthreads();
    prefix = s_pfx; rem = s_rem;
    __syncthreads();
  }
  const unsigned T = prefix;
  const int needed = rem;

  // prefix-rank over ==T elements (lowest-index tie-break, matches jax top_k)
  const int CH = 10;
  int i0 = t * CH;
  int i1 = i0 + CH; if (i1 > NNODES) i1 = NNODES;
  int loc = 0;
  for (int i = i0; i < i1; ++i)
    loc += (__float_as_uint(fabsf(s_h[i])) == T) ? 1 : 0;
  s_cnt[t] = loc;
  __syncthreads();
  for (int off = 1; off < 1024; off <<= 1) {
    int v = (t >= off) ? s_cnt[t - off] : 0;
    __syncthreads();
    s_cnt[t] += v;
    __syncthreads();
  }
  int rank = s_cnt[t] - loc;

  float a0 = 0.f, a1 = 0.f;
  for (int i = i0; i < i1; ++i) {
    float h = s_h[i];
    unsigned kk = __float_as_uint(fabsf(h));
    bool inc = false;
    if (kk > T) inc = true;
    else if (kk == T) { inc = (rank < needed); ++rank; }
    if (inc) {
      a0 += h * fc2w[i];
      a1 += h * fc2w[NNODES + i];
    }
  }
  s_red[t] = a0; __syncthreads();
  for (int off = 512; off > 0; off >>= 1) {
    if (t < off) s_red[t] += s_red[t + off];
    __syncthreads();
  }
  float r0 = s_red[0];
  __syncthreads();
  s_red[t] = a1; __syncthreads();
  for (int off = 512; off > 0; off >>= 1) {
    if (t < off) s_red[t] += s_red[t + off];
    __syncthreads();
  }
  if (t == 0) {
    out[g * 2 + 0] = r0 + fc2b[0];
    out[g * 2 + 1] = s_red[0] + fc2b[1];
  }
}

// ---------------- launch ----------------
extern "C" void kernel_launch(void* const* d_in, const int* in_sizes, int n_in,
                              void* d_out, int out_size, void* d_ws, size_t ws_size,
                              hipStream_t stream) {
  const float* tr  = (const float*)d_in[0];
  const float* x   = (const float*)d_in[1];
  const int*   ei  = (const int*)d_in[2];
  const float* adj = (const float*)d_in[4];
  const float* w1  = (const float*)d_in[5];
  const float* b1  = (const float*)d_in[6];
  const float* wr  = (const float*)d_in[7];
  const float* wn  = (const float*)d_in[8];
  const float* pb  = (const float*)d_in[9];
  const float* w2  = (const float*)d_in[10];
  const float* b2  = (const float*)d_in[11];

  char* ws = (char*)d_ws;
  float* xg       = (float*)ws;                                        // 2.56 MB
  float* partials = (float*)(ws + (size_t)NTOT * 4);                   // 4.10 MB
  int*   part_sum = (int*)(ws + (size_t)NTOT * 4 + (size_t)KSPLIT * 64 * NANNOT * 4);
  int*   part_deg = part_sum + (size_t)4 * NGRAPH * NNODES;            // 10.24 MB each
  float* out = (float*)d_out;

  dim3 g1(NANNOT / 64, KSPLIT);   // 125 x 2 = 250 blocks
  fc1_kernel<<<g1, 256, 0, stream>>>(tr, w1, adj, partials);
  finalize_kernel<<<(NTOT + 255) / 256, 256, 0, stream>>>(partials, b1, x, xg);
  agg_kernel<<<4 * NGRAPH, 1024, 0, stream>>>(ei, xg, part_sum, part_deg);
  select_kernel<<<NGRAPH, 1024, 0, stream>>>(part_sum, part_deg, xg, wr, wn, pb, w2, b2, out);
}

// Round 11
// 244.990 us; speedup vs baseline: 1.8504x; 1.1183x over previous
//
#include <hip/hip_runtime.h>
#include <hip/hip_bf16.h>

#define NGRAPH 64
#define NGENES 16000
#define NANNOT 8000
#define NNODES 10000
#define NTOT   (NGRAPH * NNODES)
#define DEG    4
#define NEDGE  (NGRAPH * NNODES * DEG)
#define KSEL   5000
#define FIXS   1048576.0f

#define KSPLIT 2
#define KSTEP  160
#define KSTEPS (NGENES / KSPLIT / KSTEP)   // 50
#define LDSROW 164                         // 160 + 4 pad ushorts (328 B row)

typedef __attribute__((ext_vector_type(8))) short bf16x8;
typedef __attribute__((ext_vector_type(4))) float f32x4;

__device__ __forceinline__ unsigned short f2bf(float x) {
  __hip_bfloat16 h = __float2bfloat16(x);   // RN
  return __builtin_bit_cast(unsigned short, h);
}
__device__ __forceinline__ float bf2f(unsigned short u) {
  unsigned int v = (unsigned int)u << 16;
  return __builtin_bit_cast(float, v);
}

// ---------------- kernel B: masked fc1, bf16x2 MFMA, 640B bursts --------------------
// partials[ksp][64 b][8000 a] = tr[64 x kslice] * (w .* adj)^T[kslice x 8000]
// A = bf16(tr) (hi only); B = w*adj as bf16 hi+lo. LDS 126 KB, dbuf, 2-deep prefetch.
__global__ __launch_bounds__(256, 1) void fc1_kernel(
    const float* __restrict__ tr, const float* __restrict__ w,
    const float* __restrict__ mk, float* __restrict__ partials) {
  __shared__ unsigned short sAh[2][64 * LDSROW];
  __shared__ unsigned short sBh[2][64 * LDSROW];
  __shared__ unsigned short sBl[2][64 * LDSROW];

  const int t = threadIdx.x;
  const int abase = blockIdx.x * 64;                 // 125 * 64 = 8000
  const int kbeg  = blockIdx.y * (NGENES / KSPLIT);  // 0 or 8000
  const int wv = t >> 6, lane = t & 63, lr = lane & 15, ls = lane >> 4;

  // flat staging map: 2560 float4 per (array, step); 10 per thread
  int soff[10], loff[10];
#pragma unroll
  for (int j = 0; j < 10; ++j) {
    int f = t + 256 * j;
    int row = f / 40, c4 = f - 40 * row;
    soff[j] = row * NGENES + c4 * 4;      // element offset within tile k-origin
    loff[j] = row * LDSROW + c4 * 4;      // ushort offset in LDS
  }
  const float* wB = w  + (size_t)abase * NGENES;
  const float* aB = mk + (size_t)abase * NGENES;

  float4 rt[10], rw[10], ra[10];

  auto load_step = [&](int k0) {
#pragma unroll
    for (int j = 0; j < 10; ++j) {
      rt[j] = *(const float4*)&tr[soff[j] + k0];
      rw[j] = *(const float4*)&wB[soff[j] + k0];
      ra[j] = *(const float4*)&aB[soff[j] + k0];
    }
  };
  auto store_step = [&](int buf) {
#pragma unroll
    for (int j = 0; j < 10; ++j) {
      ushort4 ah;
      ah.x = f2bf(rt[j].x); ah.y = f2bf(rt[j].y);
      ah.z = f2bf(rt[j].z); ah.w = f2bf(rt[j].w);
      *(ushort4*)&sAh[buf][loff[j]] = ah;
      float4 p = make_float4(rw[j].x * ra[j].x, rw[j].y * ra[j].y,
                             rw[j].z * ra[j].z, rw[j].w * ra[j].w);
      ushort4 bh, bl;
      bh.x = f2bf(p.x); bl.x = f2bf(p.x - bf2f(bh.x));
      bh.y = f2bf(p.y); bl.y = f2bf(p.y - bf2f(bh.y));
      bh.z = f2bf(p.z); bl.z = f2bf(p.z - bf2f(bh.z));
      bh.w = f2bf(p.w); bl.w = f2bf(p.w - bf2f(bh.w));
      *(ushort4*)&sBh[buf][loff[j]] = bh;
      *(ushort4*)&sBl[buf][loff[j]] = bl;
    }
  };

  f32x4 acc[4];
#pragma unroll
  for (int mt = 0; mt < 4; ++mt)
#pragma unroll
    for (int r = 0; r < 4; ++r) acc[mt][r] = 0.f;

  const int fbA = lr * LDSROW + ls * 8;
  const int fbB = (wv * 16 + lr) * LDSROW + ls * 8;

  auto compute = [&](int buf) {
#pragma unroll
    for (int ks = 0; ks < KSTEP / 32; ++ks) {
      bf16x8 bh = *(const bf16x8*)&sBh[buf][fbB + ks * 32];
      bf16x8 bl = *(const bf16x8*)&sBl[buf][fbB + ks * 32];
#pragma unroll
      for (int mt = 0; mt < 4; ++mt) {
        bf16x8 ah = *(const bf16x8*)&sAh[buf][mt * 16 * LDSROW + fbA + ks * 32];
        acc[mt] = __builtin_amdgcn_mfma_f32_16x16x32_bf16(ah, bh, acc[mt], 0, 0, 0);
        acc[mt] = __builtin_amdgcn_mfma_f32_16x16x32_bf16(ah, bl, acc[mt], 0, 0, 0);
      }
    }
  };

  load_step(kbeg);
  store_step(0);
  load_step(kbeg + KSTEP);
  __syncthreads();

#pragma unroll 1
  for (int s = 0; s < KSTEPS; ++s) {
    const int buf = s & 1;
    compute(buf);
    if (s + 1 < KSTEPS) {
      store_step(buf ^ 1);
      if (s + 2 < KSTEPS) load_step(kbeg + (s + 2) * KSTEP);
    }
    __syncthreads();
  }

  // epilogue: D col = lane&15, row = (lane>>4)*4 + reg   [m89-verified]
  float* P = partials + (size_t)blockIdx.y * (64 * NANNOT);
  const int acol = abase + wv * 16 + lr;
#pragma unroll
  for (int mt = 0; mt < 4; ++mt) {
#pragma unroll
    for (int r = 0; r < 4; ++r) {
      int b = mt * 16 + ls * 4 + r;
      P[(size_t)b * NANNOT + acol] = acc[mt][r];
    }
  }
}

// ---------------- kernel B2: finalize xg (init + deterministic k-split reduce) -----
__global__ void finalize_kernel(const float* __restrict__ partials,
                                const float* __restrict__ fc1_b,
                                const float* __restrict__ x,
                                float* __restrict__ xg) {
  int idx = blockIdx.x * blockDim.x + threadIdx.x;
  if (idx >= NTOT) return;
  int b = idx / NNODES, local = idx % NNODES;
  float s;
  if (local < NANNOT) {
    s = fc1_b[local];
    int pidx = b * NANNOT + local;
#pragma unroll
    for (int sp = 0; sp < KSPLIT; ++sp) s += partials[(size_t)sp * (64 * NANNOT) + pidx];
  } else {
    s = x[idx];
  }
  xg[idx] = s;
}

// ---------------- kernel C1: edge aggregation, 4 blocks/graph, LDS atomics ---------
__global__ __launch_bounds__(1024) void agg_kernel(
    const int* __restrict__ ei, const float* __restrict__ xg,
    int* __restrict__ part_sum, int* __restrict__ part_deg) {
  const int blk = blockIdx.x;          // 0..255
  const int g = blk >> 2, q = blk & 3;
  const int t = threadIdx.x;
  __shared__ int s_sum[NNODES];
  __shared__ int s_deg[NNODES];
  for (int i = t; i < NNODES; i += 1024) { s_sum[i] = 0; s_deg[i] = 0; }
  __syncthreads();

  const int ebase = g * (NNODES * DEG) + q * (NNODES * DEG / 4);
  const int base = g * NNODES;
  const int4* src4 = (const int4*)(ei + ebase);
  const int4* dst4 = (const int4*)(ei + NEDGE + ebase);
  const int nq = (NNODES * DEG / 4) / 4;   // 2500 int4 per quarter
  for (int v = t; v < nq; v += 1024) {
    int4 s4 = src4[v];
    int4 d4 = dst4[v];
#pragma unroll
    for (int u = 0; u < 4; ++u) {
      int s = (&s4.x)[u];
      int d = (&d4.x)[u];
      float vv = ((unsigned)s < (unsigned)NTOT) ? xg[s] : 0.f;
      unsigned dl = (unsigned)(d - base);
      if (dl < (unsigned)NNODES) {
        atomicAdd(&s_sum[dl], __float2int_rn(vv * FIXS));
        atomicAdd(&s_deg[dl], 1);
      }
    }
  }
  __syncthreads();

  int* ps = part_sum + (size_t)blk * NNODES;
  int* pd = part_deg + (size_t)blk * NNODES;
  for (int i = t; i < NNODES; i += 1024) { ps[i] = s_sum[i]; pd[i] = s_deg[i]; }
}

// ---------------- kernel C2: per-graph h + radix-select + fc2 ----------------------
__global__ __launch_bounds__(1024) void select_kernel(
    const int* __restrict__ part_sum, const int* __restrict__ part_deg,
    const float* __restrict__ xg,
    const float* __restrict__ wrp, const float* __restrict__ wnp,
    const float* __restrict__ pbp, const float* __restrict__ fc2w,
    const float* __restrict__ fc2b, float* __restrict__ out) {
  const int g = blockIdx.x;
  const int t = threadIdx.x;
  __shared__ float s_h[NNODES];
  __shared__ int s_hist[256];
  __shared__ int s_cnt[1024];
  __shared__ float s_red[1024];
  __shared__ unsigned s_pfx;
  __shared__ int s_rem;

  const int base = g * NNODES;
  const float wr = wrp[0], wn = wnp[0], pb = pbp[0];
  for (int i = t; i < NNODES; i += 1024) {
    int sum = 0, dg = 0;
#pragma unroll
    for (int q = 0; q < 4; ++q) {
      size_t off = (size_t)(g * 4 + q) * NNODES + i;
      sum += part_sum[off];
      dg  += part_deg[off];
    }
    float mean = ((float)sum * (1.0f / FIXS)) / (float)(dg > 0 ? dg : 1);
    s_h[i] = wr * xg[base + i] + wn * mean + pb;
  }
  __syncthreads();

  // radix-select the KSEL-th largest |h|; digit via parallel suffix-scan
  unsigned prefix = 0; int rem = KSEL;
  for (int byte = 3; byte >= 0; --byte) {
    const int sh = byte * 8;
    const unsigned himask = (byte == 3) ? 0u : (0xFFFFFFFFu << (sh + 8));
    if (t < 256) s_hist[t] = 0;
    __syncthreads();
    for (int i = t; i < NNODES; i += 1024) {
      unsigned kk = __float_as_uint(fabsf(s_h[i]));
      if ((kk & himask) == prefix) atomicAdd(&s_hist[(kk >> sh) & 255], 1);
    }
    __syncthreads();
    if (t < 256) s_cnt[t] = s_hist[t];
    __syncthreads();
    for (int off = 1; off < 256; off <<= 1) {
      int v = 0;
      if (t < 256 && t + off < 256) v = s_cnt[t + off];
      __syncthreads();
      if (t < 256) s_cnt[t] += v;
      __syncthreads();
    }
    if (t < 256) {
      int ge = s_cnt[t];
      int ge_next = (t == 255) ? 0 : s_cnt[t + 1];
      if (ge >= rem && ge_next < rem) {
        s_pfx = prefix | ((unsigned)t << sh);
        s_rem = rem - ge_next;
      }
    }
    __syncthreads();
    prefix = s_pfx; rem = s_rem;
    __syncthreads();
  }
  const unsigned T = prefix;
  const int needed = rem;

  // prefix-rank over ==T elements (lowest-index tie-break, matches jax top_k)
  const int CH = 10;
  int i0 = t * CH;
  int i1 = i0 + CH; if (i1 > NNODES) i1 = NNODES;
  int loc = 0;
  for (int i = i0; i < i1; ++i)
    loc += (__float_as_uint(fabsf(s_h[i])) == T) ? 1 : 0;
  s_cnt[t] = loc;
  __syncthreads();
  for (int off = 1; off < 1024; off <<= 1) {
    int v = (t >= off) ? s_cnt[t - off] : 0;
    __syncthreads();
    s_cnt[t] += v;
    __syncthreads();
  }
  int rank = s_cnt[t] - loc;

  float a0 = 0.f, a1 = 0.f;
  for (int i = i0; i < i1; ++i) {
    float h = s_h[i];
    unsigned kk = __float_as_uint(fabsf(h));
    bool inc = false;
    if (kk > T) inc = true;
    else if (kk == T) { inc = (rank < needed); ++rank; }
    if (inc) {
      a0 += h * fc2w[i];
      a1 += h * fc2w[NNODES + i];
    }
  }
  s_red[t] = a0; __syncthreads();
  for (int off = 512; off > 0; off >>= 1) {
    if (t < off) s_red[t] += s_red[t + off];
    __syncthreads();
  }
  float r0 = s_red[0];
  __syncthreads();
  s_red[t] = a1; __syncthreads();
  for (int off = 512; off > 0; off >>= 1) {
    if (t < off) s_red[t] += s_red[t + off];
    __syncthreads();
  }
  if (t == 0) {
    out[g * 2 + 0] = r0 + fc2b[0];
    out[g * 2 + 1] = s_red[0] + fc2b[1];
  }
}

// ---------------- launch ----------------
extern "C" void kernel_launch(void* const* d_in, const int* in_sizes, int n_in,
                              void* d_out, int out_size, void* d_ws, size_t ws_size,
                              hipStream_t stream) {
  const float* tr  = (const float*)d_in[0];
  const float* x   = (const float*)d_in[1];
  const int*   ei  = (const int*)d_in[2];
  const float* adj = (const float*)d_in[4];
  const float* w1  = (const float*)d_in[5];
  const float* b1  = (const float*)d_in[6];
  const float* wr  = (const float*)d_in[7];
  const float* wn  = (const float*)d_in[8];
  const float* pb  = (const float*)d_in[9];
  const float* w2  = (const float*)d_in[10];
  const float* b2  = (const float*)d_in[11];

  char* ws = (char*)d_ws;
  float* xg       = (float*)ws;                                        // 2.56 MB
  float* partials = (float*)(ws + (size_t)NTOT * 4);                   // 4.10 MB
  int*   part_sum = (int*)(ws + (size_t)NTOT * 4 + (size_t)KSPLIT * 64 * NANNOT * 4);
  int*   part_deg = part_sum + (size_t)4 * NGRAPH * NNODES;            // 10.24 MB each
  float* out = (float*)d_out;

  dim3 g1(NANNOT / 64, KSPLIT);   // 125 x 2 = 250 blocks
  fc1_kernel<<<g1, 256, 0, stream>>>(tr, w1, adj, partials);
  finalize_kernel<<<(NTOT + 255) / 256, 256, 0, stream>>>(partials, b1, x, xg);
  agg_kernel<<<4 * NGRAPH, 1024, 0, stream>>>(ei, xg, part_sum, part_deg);
  select_kernel<<<NGRAPH, 1024, 0, stream>>>(part_sum, part_deg, xg, wr, wn, pb, w2, b2, out);
}

// Round 12
// 240.126 us; speedup vs baseline: 1.8879x; 1.0203x over previous
//
#include <hip/hip_runtime.h>
#include <hip/hip_bf16.h>

#define NGRAPH 64
#define NGENES 16000
#define NANNOT 8000
#define NNODES 10000
#define NTOT   (NGRAPH * NNODES)
#define DEG    4
#define NEDGE  (NGRAPH * NNODES * DEG)
#define KSEL   5000
#define FIXS   1048576.0f

#define KSPLIT 2
#define KSTEP  160
#define KSTEPS (NGENES / KSPLIT / KSTEP)   // 50
#define LDSROW 164                         // 160 + 4 pad ushorts (328 B row)

typedef __attribute__((ext_vector_type(8))) short bf16x8;
typedef __attribute__((ext_vector_type(4))) float f32x4;

__device__ __forceinline__ unsigned short f2bf(float x) {
  __hip_bfloat16 h = __float2bfloat16(x);   // RN
  return __builtin_bit_cast(unsigned short, h);
}
__device__ __forceinline__ float bf2f(unsigned short u) {
  unsigned int v = (unsigned int)u << 16;
  return __builtin_bit_cast(float, v);
}

// ---------------- kernel B: masked fc1, bf16x2 MFMA, 640B bursts (r11 proven) -------
__global__ __launch_bounds__(256, 1) void fc1_kernel(
    const float* __restrict__ tr, const float* __restrict__ w,
    const float* __restrict__ mk, float* __restrict__ partials) {
  __shared__ unsigned short sAh[2][64 * LDSROW];
  __shared__ unsigned short sBh[2][64 * LDSROW];
  __shared__ unsigned short sBl[2][64 * LDSROW];

  const int t = threadIdx.x;
  const int abase = blockIdx.x * 64;                 // 125 * 64 = 8000
  const int kbeg  = blockIdx.y * (NGENES / KSPLIT);  // 0 or 8000
  const int wv = t >> 6, lane = t & 63, lr = lane & 15, ls = lane >> 4;

  int soff[10], loff[10];
#pragma unroll
  for (int j = 0; j < 10; ++j) {
    int f = t + 256 * j;
    int row = f / 40, c4 = f - 40 * row;
    soff[j] = row * NGENES + c4 * 4;
    loff[j] = row * LDSROW + c4 * 4;
  }
  const float* wB = w  + (size_t)abase * NGENES;
  const float* aB = mk + (size_t)abase * NGENES;

  float4 rt[10], rw[10], ra[10];

  auto load_step = [&](int k0) {
#pragma unroll
    for (int j = 0; j < 10; ++j) {
      rt[j] = *(const float4*)&tr[soff[j] + k0];
      rw[j] = *(const float4*)&wB[soff[j] + k0];
      ra[j] = *(const float4*)&aB[soff[j] + k0];
    }
  };
  auto store_step = [&](int buf) {
#pragma unroll
    for (int j = 0; j < 10; ++j) {
      ushort4 ah;
      ah.x = f2bf(rt[j].x); ah.y = f2bf(rt[j].y);
      ah.z = f2bf(rt[j].z); ah.w = f2bf(rt[j].w);
      *(ushort4*)&sAh[buf][loff[j]] = ah;
      float4 p = make_float4(rw[j].x * ra[j].x, rw[j].y * ra[j].y,
                             rw[j].z * ra[j].z, rw[j].w * ra[j].w);
      ushort4 bh, bl;
      bh.x = f2bf(p.x); bl.x = f2bf(p.x - bf2f(bh.x));
      bh.y = f2bf(p.y); bl.y = f2bf(p.y - bf2f(bh.y));
      bh.z = f2bf(p.z); bl.z = f2bf(p.z - bf2f(bh.z));
      bh.w = f2bf(p.w); bl.w = f2bf(p.w - bf2f(bh.w));
      *(ushort4*)&sBh[buf][loff[j]] = bh;
      *(ushort4*)&sBl[buf][loff[j]] = bl;
    }
  };

  f32x4 acc[4];
#pragma unroll
  for (int mt = 0; mt < 4; ++mt)
#pragma unroll
    for (int r = 0; r < 4; ++r) acc[mt][r] = 0.f;

  const int fbA = lr * LDSROW + ls * 8;
  const int fbB = (wv * 16 + lr) * LDSROW + ls * 8;

  auto compute = [&](int buf) {
#pragma unroll
    for (int ks = 0; ks < KSTEP / 32; ++ks) {
      bf16x8 bh = *(const bf16x8*)&sBh[buf][fbB + ks * 32];
      bf16x8 bl = *(const bf16x8*)&sBl[buf][fbB + ks * 32];
#pragma unroll
      for (int mt = 0; mt < 4; ++mt) {
        bf16x8 ah = *(const bf16x8*)&sAh[buf][mt * 16 * LDSROW + fbA + ks * 32];
        acc[mt] = __builtin_amdgcn_mfma_f32_16x16x32_bf16(ah, bh, acc[mt], 0, 0, 0);
        acc[mt] = __builtin_amdgcn_mfma_f32_16x16x32_bf16(ah, bl, acc[mt], 0, 0, 0);
      }
    }
  };

  load_step(kbeg);
  store_step(0);
  load_step(kbeg + KSTEP);
  __syncthreads();

#pragma unroll 1
  for (int s = 0; s < KSTEPS; ++s) {
    const int buf = s & 1;
    compute(buf);
    if (s + 1 < KSTEPS) {
      store_step(buf ^ 1);
      if (s + 2 < KSTEPS) load_step(kbeg + (s + 2) * KSTEP);
    }
    __syncthreads();
  }

  float* P = partials + (size_t)blockIdx.y * (64 * NANNOT);
  const int acol = abase + wv * 16 + lr;
#pragma unroll
  for (int mt = 0; mt < 4; ++mt) {
#pragma unroll
    for (int r = 0; r < 4; ++r) {
      int b = mt * 16 + ls * 4 + r;
      P[(size_t)b * NANNOT + acol] = acc[mt][r];
    }
  }
}

// ---------------- kernel B2: finalize xg, float4 (branch uniform per quad) ---------
__global__ void finalize_kernel(const float4* __restrict__ partials4,
                                const float* __restrict__ fc1_b,
                                const float4* __restrict__ x4,
                                float4* __restrict__ xg4) {
  int idx4 = blockIdx.x * blockDim.x + threadIdx.x;
  if (idx4 >= NTOT / 4) return;
  int idx = idx4 * 4;
  int b = idx / NNODES, local = idx - b * NNODES;
  float4 o;
  if (local < NANNOT) {
    int p4 = (b * NANNOT + local) >> 2;
    float4 s0 = partials4[p4];
    float4 s1 = partials4[(64 * NANNOT) / 4 + p4];
    const float4 bb = *(const float4*)&fc1_b[local];
    o = make_float4(bb.x + s0.x + s1.x, bb.y + s0.y + s1.y,
                    bb.z + s0.z + s1.z, bb.w + s0.w + s1.w);
  } else {
    o = x4[idx4];
  }
  xg4[idx4] = o;
}

// ---------------- kernel C1: edge aggregation, 4 blocks/graph, LDS atomics ---------
__global__ __launch_bounds__(1024) void agg_kernel(
    const int* __restrict__ ei, const float* __restrict__ xg,
    int* __restrict__ part_sum, int* __restrict__ part_deg) {
  const int blk = blockIdx.x;          // 0..255
  const int g = blk >> 2, q = blk & 3;
  const int t = threadIdx.x;
  __shared__ int s_sum[NNODES];
  __shared__ int s_deg[NNODES];
  for (int i = t; i < NNODES; i += 1024) { s_sum[i] = 0; s_deg[i] = 0; }
  __syncthreads();

  const int ebase = g * (NNODES * DEG) + q * (NNODES * DEG / 4);
  const int base = g * NNODES;
  const int4* src4 = (const int4*)(ei + ebase);
  const int4* dst4 = (const int4*)(ei + NEDGE + ebase);
  const int nq = (NNODES * DEG / 4) / 4;   // 2500
  for (int v = t; v < nq; v += 1024) {
    int4 s4 = src4[v];
    int4 d4 = dst4[v];
#pragma unroll
    for (int u = 0; u < 4; ++u) {
      int s = (&s4.x)[u];
      int d = (&d4.x)[u];
      float vv = ((unsigned)s < (unsigned)NTOT) ? xg[s] : 0.f;
      unsigned dl = (unsigned)(d - base);
      if (dl < (unsigned)NNODES) {
        atomicAdd(&s_sum[dl], __float2int_rn(vv * FIXS));
        atomicAdd(&s_deg[dl], 1);
      }
    }
  }
  __syncthreads();

  int* ps = part_sum + (size_t)blk * NNODES;
  int* pd = part_deg + (size_t)blk * NNODES;
  for (int i = t; i < NNODES; i += 1024) { ps[i] = s_sum[i]; pd[i] = s_deg[i]; }
}

// ---------------- kernel C2: per-graph h + 2-pass radix select + fc2 ---------------
__global__ __launch_bounds__(1024) void select_kernel(
    const int* __restrict__ part_sum, const int* __restrict__ part_deg,
    const float* __restrict__ xg,
    const float* __restrict__ wrp, const float* __restrict__ wnp,
    const float* __restrict__ pbp, const float* __restrict__ fc2w,
    const float* __restrict__ fc2b, float* __restrict__ out) {
  const int g = blockIdx.x;
  const int t = threadIdx.x;
  const int lane = t & 63, wid = t >> 6;
  __shared__ float s_h[NNODES];
  __shared__ int s_hist[256];
  __shared__ int s_cnt[256];
  __shared__ float s_red[1024];
  __shared__ int s_wsum[16];
  __shared__ int s_wpre[16];
  __shared__ unsigned s_pfx;
  __shared__ int s_rem;

  const int base = g * NNODES;
  const float wr = wrp[0], wn = wnp[0], pb = pbp[0];
  for (int i = t; i < NNODES; i += 1024) {
    int sum = 0, dg = 0;
#pragma unroll
    for (int q = 0; q < 4; ++q) {
      size_t off = (size_t)(g * 4 + q) * NNODES + i;
      sum += part_sum[off];
      dg  += part_deg[off];
    }
    float mean = ((float)sum * (1.0f / FIXS)) / (float)(dg > 0 ? dg : 1);
    s_h[i] = wr * xg[base + i] + wn * mean + pb;
  }
  __syncthreads();

  // 2-pass radix: find top-16-bit prefix T such that
  // #(key>>16 > T>>16) < KSEL <= #(key>>16 >= T>>16); rank-gate prefix-ties.
  unsigned prefix = 0; int rem = KSEL;
#pragma unroll
  for (int pass = 0; pass < 2; ++pass) {
    const int sh = (3 - pass) * 8;
    const unsigned himask = (pass == 0) ? 0u : 0xFF000000u;
    if (t < 256) s_hist[t] = 0;
    __syncthreads();
    for (int i = t; i < NNODES; i += 1024) {
      unsigned kk = __float_as_uint(fabsf(s_h[i]));
      if ((kk & himask) == prefix) atomicAdd(&s_hist[(kk >> sh) & 255], 1);
    }
    __syncthreads();
    // wave 0: suffix sums of 256 bins (4 bins/lane), no inner barriers
    if (wid == 0) {
      int h0 = s_hist[4 * lane], h1 = s_hist[4 * lane + 1];
      int h2 = s_hist[4 * lane + 2], h3 = s_hist[4 * lane + 3];
      int lt = h0 + h1 + h2 + h3;
      int sfx = lt;
#pragma unroll
      for (int off = 1; off < 64; off <<= 1) {
        int o = __shfl_down(sfx, off);
        sfx += (lane + off < 64) ? o : 0;
      }
      int above = sfx - lt;                  // sum over lanes > lane
      int ge3 = above + h3;
      int ge2 = ge3 + h2;
      int ge1 = ge2 + h1;
      int ge0 = ge1 + h0;
      s_cnt[4 * lane]     = ge0;
      s_cnt[4 * lane + 1] = ge1;
      s_cnt[4 * lane + 2] = ge2;
      s_cnt[4 * lane + 3] = ge3;
    }
    __syncthreads();
    if (t < 256) {
      int ge = s_cnt[t];
      int ge_next = (t == 255) ? 0 : s_cnt[t + 1];
      if (ge >= rem && ge_next < rem) {
        s_pfx = prefix | ((unsigned)t << sh);
        s_rem = rem - ge_next;
      }
    }
    __syncthreads();
    prefix = s_pfx; rem = s_rem;
    __syncthreads();
  }
  const unsigned T = prefix;                 // high-16 threshold (low 16 zero)
  const int needed = rem;

  // rank over prefix-tie elements (lowest-index first), shfl-based scan
  const int CH = 10;
  int i0 = t * CH;
  int i1 = i0 + CH; if (i1 > NNODES) i1 = NNODES;
  int loc = 0;
  for (int i = i0; i < i1; ++i)
    loc += ((__float_as_uint(fabsf(s_h[i])) & 0xFFFF0000u) == T) ? 1 : 0;
  int incl = loc;
#pragma unroll
  for (int off = 1; off < 64; off <<= 1) {
    int o = __shfl_up(incl, off);
    if (lane >= off) incl += o;
  }
  if (lane == 63) s_wsum[wid] = incl;
  __syncthreads();
  if (t < 64) {
    int v = (lane < 16) ? s_wsum[lane] : 0;
    int inc16 = v;
#pragma unroll
    for (int off = 1; off < 16; off <<= 1) {
      int o = __shfl_up(inc16, off);
      if (lane >= off) inc16 += o;
    }
    if (lane < 16) s_wpre[lane] = inc16 - v;   // exclusive wave prefix
  }
  __syncthreads();
  int rank = s_wpre[wid] + (incl - loc);

  float a0 = 0.f, a1 = 0.f;
  for (int i = i0; i < i1; ++i) {
    float h = s_h[i];
    unsigned kp = __float_as_uint(fabsf(h)) & 0xFFFF0000u;
    bool inc = false;
    if (kp > T) inc = true;
    else if (kp == T) { inc = (rank < needed); ++rank; }
    if (inc) {
      a0 += h * fc2w[i];
      a1 += h * fc2w[NNODES + i];
    }
  }
  s_red[t] = a0; __syncthreads();
  for (int off = 512; off > 0; off >>= 1) {
    if (t < off) s_red[t] += s_red[t + off];
    __syncthreads();
  }
  float r0 = s_red[0];
  __syncthreads();
  s_red[t] = a1; __syncthreads();
  for (int off = 512; off > 0; off >>= 1) {
    if (t < off) s_red[t] += s_red[t + off];
    __syncthreads();
  }
  if (t == 0) {
    out[g * 2 + 0] = r0 + fc2b[0];
    out[g * 2 + 1] = s_red[0] + fc2b[1];
  }
}

// ---------------- launch ----------------
extern "C" void kernel_launch(void* const* d_in, const int* in_sizes, int n_in,
                              void* d_out, int out_size, void* d_ws, size_t ws_size,
                              hipStream_t stream) {
  const float* tr  = (const float*)d_in[0];
  const float* x   = (const float*)d_in[1];
  const int*   ei  = (const int*)d_in[2];
  const float* adj = (const float*)d_in[4];
  const float* w1  = (const float*)d_in[5];
  const float* b1  = (const float*)d_in[6];
  const float* wr  = (const float*)d_in[7];
  const float* wn  = (const float*)d_in[8];
  const float* pb  = (const float*)d_in[9];
  const float* w2  = (const float*)d_in[10];
  const float* b2  = (const float*)d_in[11];

  char* ws = (char*)d_ws;
  float* xg       = (float*)ws;                                        // 2.56 MB
  float* partials = (float*)(ws + (size_t)NTOT * 4);                   // 4.10 MB
  int*   part_sum = (int*)(ws + (size_t)NTOT * 4 + (size_t)KSPLIT * 64 * NANNOT * 4);
  int*   part_deg = part_sum + (size_t)4 * NGRAPH * NNODES;            // 10.24 MB each
  float* out = (float*)d_out;

  dim3 g1(NANNOT / 64, KSPLIT);   // 125 x 2 = 250 blocks
  fc1_kernel<<<g1, 256, 0, stream>>>(tr, w1, adj, partials);
  finalize_kernel<<<(NTOT / 4 + 255) / 256, 256, 0, stream>>>(
      (const float4*)partials, b1, (const float4*)x, (float4*)xg);
  agg_kernel<<<4 * NGRAPH, 1024, 0, stream>>>(ei, xg, part_sum, part_deg);
  select_kernel<<<NGRAPH, 1024, 0, stream>>>(part_sum, part_deg, xg, wr, wn, pb, w2, b2, out);
}